// Round 1
// baseline (134.117 us; speedup 1.0000x reference)
//
#include <hip/hip_runtime.h>
#include <cstdint>
#include <cstddef>

typedef _Float16 f16;
typedef _Float16 f16x4 __attribute__((ext_vector_type(4)));
typedef _Float16 f16x8 __attribute__((ext_vector_type(8)));
typedef float f32x4 __attribute__((ext_vector_type(4)));

#define MFMA16(a, b, c) __builtin_amdgcn_mfma_f32_16x16x32_f16(a, b, c, 0, 0, 0)

static __device__ __forceinline__ void gld16(const void* g, void* l) {
  __builtin_amdgcn_global_load_lds(
      (const __attribute__((address_space(1))) void*)g,
      (__attribute__((address_space(3))) void*)l, 16, 0, 0);
}

#define B_ 4
#define N_ 4096
#define C_ 512
#define H_ 8
#define D_ 64
#define BN_ROWS 16384
#define QKV_COLS 1536

// ---------------- kernel 1: fp32 -> fp16 convert (x, Wqkv, Wproj) ----------------
__global__ __launch_bounds__(256) void k_convert(
    const float* __restrict__ x, const float* __restrict__ wqkv,
    const float* __restrict__ wproj,
    f16* __restrict__ xh, f16* __restrict__ wqkvh, f16* __restrict__ wprojh)
{
  const int NX  = (BN_ROWS * C_) / 4;   // 2097152 float4
  const int NW1 = (QKV_COLS * C_) / 4;  // 196608
  const int NW2 = (C_ * C_) / 4;        // 65536
  const int total = NX + NW1 + NW2;
  const int stride = gridDim.x * blockDim.x;
  for (int i = blockIdx.x * blockDim.x + threadIdx.x; i < total; i += stride) {
    const float4* s; f16x4* d; int j;
    if (i < NX)              { s = (const float4*)x;     d = (f16x4*)xh;     j = i; }
    else if (i < NX + NW1)   { s = (const float4*)wqkv;  d = (f16x4*)wqkvh;  j = i - NX; }
    else                     { s = (const float4*)wproj; d = (f16x4*)wprojh; j = i - NX - NW1; }
    float4 v = s[j];
    f16x4 o; o[0] = (f16)v.x; o[1] = (f16)v.y; o[2] = (f16)v.z; o[3] = (f16)v.w;
    d[j] = o;
  }
}

// ---------------- kernel 2: QKV GEMM  C(16384x1536) = X(16384x512) @ W(1536x512)^T
// ReLU fused on cols < 1024 (q and k). fp16 out.
__global__ __launch_bounds__(256) void k_qkv_gemm(
    const f16* __restrict__ X, const f16* __restrict__ W, f16* __restrict__ Out)
{
  __shared__ f16 As[128][64];
  __shared__ f16 Bs[128][64];
  const int tid = threadIdx.x;
  const int wid = tid >> 6;
  const int lane = tid & 63;
  const int lr = lane & 15, lg = lane >> 4;
  const int m0 = blockIdx.y * 128;
  const int n0 = blockIdx.x * 128;
  const int srow = lane >> 3, scol = (lane & 7) * 8;
  const int wr = (wid >> 1) * 64, wc = (wid & 1) * 64;
  f32x4 acc[4][4] = {};
  for (int kt = 0; kt < 512; kt += 64) {
#pragma unroll
    for (int i = 0; i < 4; ++i) {
      int chunk = wid * 4 + i;
      int row = chunk * 8 + srow;
      gld16(&X[(size_t)(m0 + row) * 512 + kt + scol], &As[chunk * 8][0]);
      gld16(&W[(size_t)(n0 + row) * 512 + kt + scol], &Bs[chunk * 8][0]);
    }
    __syncthreads();
#pragma unroll
    for (int kk = 0; kk < 2; ++kk) {
      f16x8 af[4], bf[4];
#pragma unroll
      for (int m = 0; m < 4; ++m) af[m] = *(const f16x8*)&As[wr + m * 16 + lr][kk * 32 + lg * 8];
#pragma unroll
      for (int n = 0; n < 4; ++n) bf[n] = *(const f16x8*)&Bs[wc + n * 16 + lr][kk * 32 + lg * 8];
#pragma unroll
      for (int m = 0; m < 4; ++m)
#pragma unroll
        for (int n = 0; n < 4; ++n)
          acc[m][n] = MFMA16(af[m], bf[n], acc[m][n]);
    }
    __syncthreads();
  }
#pragma unroll
  for (int m = 0; m < 4; ++m)
#pragma unroll
    for (int n = 0; n < 4; ++n)
#pragma unroll
      for (int j = 0; j < 4; ++j) {
        int row = m0 + wr + m * 16 + lg * 4 + j;
        int col = n0 + wc + n * 16 + lr;
        float v = acc[m][n][j];
        if (col < 1024) v = fmaxf(v, 0.f);  // relu(q), relu(k)
        Out[(size_t)row * QKV_COLS + col] = (f16)v;
      }
}

// ---------------- kernel 3: partial K^T V (64x64 per bh) + partial ksum ----------------
// grid (32 bh, 8 splits), 256 threads. fp32 outer-product accumulation.
__global__ __launch_bounds__(256) void k_ktv(
    const f16* __restrict__ qkv, float* __restrict__ partial, float* __restrict__ pksum)
{
  __shared__ f16 ks[32][64];
  __shared__ f16 vs[32][64];
  const int bh = blockIdx.x, sp = blockIdx.y;
  const int b = bh >> 3, h = bh & 7;
  const int tid = threadIdx.x, wid = tid >> 6, lane = tid & 63;
  const int srow = lane >> 3, scol = (lane & 7) * 8;
  const int td = (wid << 2) | (lane >> 4);  // 0..15  (d block)
  const int te = lane & 15;                 // 0..15  (e block)
  float acc[4][4] = {};
  float ksacc[4] = {0.f, 0.f, 0.f, 0.f};
  const size_t rowbase = (size_t)b * N_ + sp * 512;
  for (int t = 0; t < 16; ++t) {
    int nb = t * 32 + wid * 8 + srow;
    gld16(&qkv[(rowbase + nb) * QKV_COLS + 512 + h * 64 + scol], &ks[wid * 8][0]);
    gld16(&qkv[(rowbase + nb) * QKV_COLS + 1024 + h * 64 + scol], &vs[wid * 8][0]);
    __syncthreads();
#pragma unroll 4
    for (int n = 0; n < 32; ++n) {
      f16x4 kd = *(const f16x4*)&ks[n][td * 4];
      f16x4 ve = *(const f16x4*)&vs[n][te * 4];
      float kf[4], vf[4];
#pragma unroll
      for (int i = 0; i < 4; ++i) { kf[i] = (float)kd[i]; vf[i] = (float)ve[i]; }
#pragma unroll
      for (int i = 0; i < 4; ++i)
#pragma unroll
        for (int j = 0; j < 4; ++j)
          acc[i][j] += kf[i] * vf[j];
      if (te == 0) {
#pragma unroll
        for (int i = 0; i < 4; ++i) ksacc[i] += kf[i];
      }
    }
    __syncthreads();
  }
  float* pp = partial + (size_t)(bh * 8 + sp) * 4096;
#pragma unroll
  for (int i = 0; i < 4; ++i)
#pragma unroll
    for (int j = 0; j < 4; ++j)
      pp[(td * 4 + i) * 64 + te * 4 + j] = acc[i][j];
  if (te == 0) {
    float* kp = pksum + (bh * 8 + sp) * 64;
#pragma unroll
    for (int i = 0; i < 4; ++i) kp[td * 4 + i] = ksacc[i];
  }
}

// ---------------- kernel 4: reduce 8 partials (deterministic) ----------------
__global__ __launch_bounds__(256) void k_reduce(
    const float* __restrict__ partial, const float* __restrict__ pksum,
    float* __restrict__ attn_acc, float* __restrict__ ksum)
{
  const int bh = blockIdx.x, seg = blockIdx.y, tid = threadIdx.x;
  const int i = seg * 256 + tid;
  float s = 0.f;
#pragma unroll
  for (int sp = 0; sp < 8; ++sp) s += partial[(size_t)(bh * 8 + sp) * 4096 + i];
  attn_acc[bh * 4096 + i] = s;
  if (seg == 0 && tid < 64) {
    float t2 = 0.f;
#pragma unroll
    for (int sp = 0; sp < 8; ++sp) t2 += pksum[(bh * 8 + sp) * 64 + tid];
    ksum[bh * 64 + tid] = t2;
  }
}

// ---------------- kernel 5: attn1 = q @ (attn*temp); denom; outputs ----------------
// grid (32 bh, 16 n-splits of 256 rows), 256 threads.
__global__ __launch_bounds__(256) void k_attn1(
    const f16* __restrict__ qkv, const float* __restrict__ attn_acc,
    const float* __restrict__ ksum, const float* __restrict__ temp,
    float* __restrict__ attn1_out, f16* __restrict__ outh)
{
  __shared__ f16 attnT[64][64];   // attnT[e][d] = attn[d][e] * temperature[h]
  __shared__ float ksum_s[64];
  __shared__ float denom_s[256];
  const int bh = blockIdx.x, sp = blockIdx.y;
  const int b = bh >> 3, h = bh & 7;
  const int tid = threadIdx.x, wid = tid >> 6, lane = tid & 63;
  const int lr = lane & 15, lg = lane >> 4;
  const int n0 = sp * 256;
  const float tscale = temp[h];
  for (int i = tid; i < 4096; i += 256) {
    int d = i >> 6, e = i & 63;
    attnT[e][d] = (f16)(attn_acc[bh * 4096 + i] * tscale);
  }
  if (tid < 64) ksum_s[tid] = ksum[bh * 64 + tid];
  __syncthreads();
  {  // denom for this thread's row
    size_t row = (size_t)b * N_ + n0 + tid;
    const f16* qrow = &qkv[row * QKV_COLS + h * 64];
    float dot = 0.f;
#pragma unroll
    for (int d0 = 0; d0 < 64; d0 += 8) {
      f16x8 qv = *(const f16x8*)&qrow[d0];
#pragma unroll
      for (int j = 0; j < 8; ++j) dot += (float)qv[j] * ksum_s[d0 + j];
    }
    denom_s[tid] = fmaxf(dot, 100.f);
  }
  // B fragments: B[k=d][n=e] = attnT[e][d], row-contiguous reads
  f16x8 bf[4][2];
#pragma unroll
  for (int et = 0; et < 4; ++et)
#pragma unroll
    for (int kk = 0; kk < 2; ++kk)
      bf[et][kk] = *(const f16x8*)&attnT[et * 16 + lr][kk * 32 + lg * 8];
  __syncthreads();
  f32x4 acc[4][4] = {};
#pragma unroll
  for (int mt = 0; mt < 4; ++mt) {
    size_t rbase = ((size_t)b * N_ + n0 + wid * 64 + mt * 16 + lr) * QKV_COLS + h * 64;
#pragma unroll
    for (int kk = 0; kk < 2; ++kk) {
      f16x8 a = *(const f16x8*)&qkv[rbase + kk * 32 + lg * 8];
#pragma unroll
      for (int et = 0; et < 4; ++et)
        acc[mt][et] = MFMA16(a, bf[et][kk], acc[mt][et]);
    }
  }
#pragma unroll
  for (int mt = 0; mt < 4; ++mt)
#pragma unroll
    for (int et = 0; et < 4; ++et)
#pragma unroll
      for (int j = 0; j < 4; ++j) {
        int rl = wid * 64 + mt * 16 + lg * 4 + j;
        int n = n0 + rl;
        int e = et * 16 + lr;
        float v = acc[mt][et][j];
        attn1_out[((size_t)bh * N_ + n) * 64 + e] = v;
        outh[((size_t)b * N_ + n) * 512 + h * 64 + e] = (f16)(v / denom_s[rl]);
      }
}

// ---------------- kernel 6: proj GEMM  Y(16384x512) = out(16384x512) @ Wproj(512x512)^T + b
__global__ __launch_bounds__(256) void k_proj_gemm(
    const f16* __restrict__ X, const f16* __restrict__ W,
    const float* __restrict__ bias, float* __restrict__ Y)
{
  __shared__ f16 As[128][64];
  __shared__ f16 Bs[128][64];
  const int tid = threadIdx.x;
  const int wid = tid >> 6;
  const int lane = tid & 63;
  const int lr = lane & 15, lg = lane >> 4;
  const int m0 = blockIdx.y * 128;
  const int n0 = blockIdx.x * 128;
  const int srow = lane >> 3, scol = (lane & 7) * 8;
  const int wr = (wid >> 1) * 64, wc = (wid & 1) * 64;
  f32x4 acc[4][4] = {};
  for (int kt = 0; kt < 512; kt += 64) {
#pragma unroll
    for (int i = 0; i < 4; ++i) {
      int chunk = wid * 4 + i;
      int row = chunk * 8 + srow;
      gld16(&X[(size_t)(m0 + row) * 512 + kt + scol], &As[chunk * 8][0]);
      gld16(&W[(size_t)(n0 + row) * 512 + kt + scol], &Bs[chunk * 8][0]);
    }
    __syncthreads();
#pragma unroll
    for (int kk = 0; kk < 2; ++kk) {
      f16x8 af[4], bf[4];
#pragma unroll
      for (int m = 0; m < 4; ++m) af[m] = *(const f16x8*)&As[wr + m * 16 + lr][kk * 32 + lg * 8];
#pragma unroll
      for (int n = 0; n < 4; ++n) bf[n] = *(const f16x8*)&Bs[wc + n * 16 + lr][kk * 32 + lg * 8];
#pragma unroll
      for (int m = 0; m < 4; ++m)
#pragma unroll
        for (int n = 0; n < 4; ++n)
          acc[m][n] = MFMA16(af[m], bf[n], acc[m][n]);
    }
    __syncthreads();
  }
#pragma unroll
  for (int m = 0; m < 4; ++m)
#pragma unroll
    for (int n = 0; n < 4; ++n)
#pragma unroll
      for (int j = 0; j < 4; ++j) {
        int row = m0 + wr + m * 16 + lg * 4 + j;
        int col = n0 + wc + n * 16 + lr;
        Y[(size_t)row * C_ + col] = acc[m][n][j] + bias[col];
      }
}

extern "C" void kernel_launch(void* const* d_in, const int* in_sizes, int n_in,
                              void* d_out, int out_size, void* d_ws, size_t ws_size,
                              hipStream_t stream)
{
  const float* x     = (const float*)d_in[0];
  const float* wqkv  = (const float*)d_in[1];
  const float* temp  = (const float*)d_in[2];
  const float* wproj = (const float*)d_in[3];
  const float* bproj = (const float*)d_in[4];
  float* y_out     = (float*)d_out;               // (B,N,C) = 8388608 floats
  float* attn1_out = (float*)d_out + 8388608;     // (B,H,N,D) = 8388608 floats

  char* ws = (char*)d_ws;
  f16*   xh       = (f16*)(ws);                   // 16777216 B
  f16*   wqkvh    = (f16*)(ws + 16777216);        // 1572864
  f16*   wprojh   = (f16*)(ws + 18350080);        // 524288
  f16*   qkvh     = (f16*)(ws + 18874368);        // 50331648
  float* partial  = (float*)(ws + 69206016);      // 4194304
  float* pksum    = (float*)(ws + 73400320);      // 65536
  float* attn_acc = (float*)(ws + 73465856);      // 524288
  float* ksum     = (float*)(ws + 73990144);      // 8192
  f16*   outh     = (f16*)(ws + 73998336);        // 16777216 (end 90775552)

  hipLaunchKernelGGL(k_convert,  dim3(2048),    dim3(256), 0, stream, x, wqkv, wproj, xh, wqkvh, wprojh);
  hipLaunchKernelGGL(k_qkv_gemm, dim3(12, 128), dim3(256), 0, stream, xh, wqkvh, qkvh);
  hipLaunchKernelGGL(k_ktv,      dim3(32, 8),   dim3(256), 0, stream, qkvh, partial, pksum);
  hipLaunchKernelGGL(k_reduce,   dim3(32, 16),  dim3(256), 0, stream, partial, pksum, attn_acc, ksum);
  hipLaunchKernelGGL(k_attn1,    dim3(32, 16),  dim3(256), 0, stream, qkvh, attn_acc, ksum, temp, attn1_out, outh);
  hipLaunchKernelGGL(k_proj_gemm,dim3(4, 128),  dim3(256), 0, stream, outh, wprojh, bproj, y_out);
}

// Round 2
// 123.126 us; speedup vs baseline: 1.0893x; 1.0893x over previous
//
#include <hip/hip_runtime.h>
#include <cstdint>
#include <cstddef>

typedef _Float16 f16;
typedef _Float16 f16x4 __attribute__((ext_vector_type(4)));
typedef _Float16 f16x8 __attribute__((ext_vector_type(8)));
typedef float f32x4 __attribute__((ext_vector_type(4)));

#define MFMA16(a, b, c) __builtin_amdgcn_mfma_f32_16x16x32_f16(a, b, c, 0, 0, 0)

static __device__ __forceinline__ void gld16(const void* g, void* l) {
  __builtin_amdgcn_global_load_lds(
      (const __attribute__((address_space(1))) void*)g,
      (__attribute__((address_space(3))) void*)l, 16, 0, 0);
}

#define B_ 4
#define N_ 4096
#define C_ 512
#define H_ 8
#define D_ 64
#define BN_ROWS 16384
#define QKV_COLS 1536

// ---------------- kernel 1: fp32 -> fp16 convert (x, Wqkv, Wproj) ----------------
__global__ __launch_bounds__(256) void k_convert(
    const float* __restrict__ x, const float* __restrict__ wqkv,
    const float* __restrict__ wproj,
    f16* __restrict__ xh, f16* __restrict__ wqkvh, f16* __restrict__ wprojh)
{
  const int NX  = (BN_ROWS * C_) / 4;
  const int NW1 = (QKV_COLS * C_) / 4;
  const int NW2 = (C_ * C_) / 4;
  const int total = NX + NW1 + NW2;
  const int stride = gridDim.x * blockDim.x;
  for (int i = blockIdx.x * blockDim.x + threadIdx.x; i < total; i += stride) {
    const float4* s; f16x4* d; int j;
    if (i < NX)              { s = (const float4*)x;     d = (f16x4*)xh;     j = i; }
    else if (i < NX + NW1)   { s = (const float4*)wqkv;  d = (f16x4*)wqkvh;  j = i - NX; }
    else                     { s = (const float4*)wproj; d = (f16x4*)wprojh; j = i - NX - NW1; }
    float4 v = s[j];
    f16x4 o; o[0] = (f16)v.x; o[1] = (f16)v.y; o[2] = (f16)v.z; o[3] = (f16)v.w;
    d[j] = o;
  }
}

// ---------------- kernel 2: QKV GEMM  C(16384x1536) = X(16384x512) @ W(1536x512)^T
// T2 XOR-swizzled LDS (pre-swizzled global src), swapped-operand MFMA for
// vectorized f16x4 stores, XCD-aware block swizzle. ReLU fused on cols < 1024.
__global__ __launch_bounds__(256) void k_qkv_gemm(
    const f16* __restrict__ X, const f16* __restrict__ W, f16* __restrict__ Out)
{
  __shared__ f16 As[128][64];
  __shared__ f16 Bs[128][64];
  // XCD swizzle: 1536 blocks, 8 XCDs, 192 consecutive work-ids per XCD
  int w = (blockIdx.x & 7) * 192 + (blockIdx.x >> 3);
  const int n0 = (w % 12) * 128;
  const int m0 = (w / 12) * 128;
  const int tid = threadIdx.x;
  const int wid = tid >> 6;
  const int lane = tid & 63;
  const int lr = lane & 15, lg = lane >> 4;
  // staging: lane -> row r within 8-row chunk, slot s; source slot d = s ^ r
  const int sr = lane >> 3;             // 0..7
  const int sslot = (lane & 7) ^ sr;    // pre-swizzled source 16B-slot
  const int wr = (wid >> 1) * 64, wc = (wid & 1) * 64;
  f32x4 acc[4][4] = {};
  for (int kt = 0; kt < 512; kt += 64) {
#pragma unroll
    for (int i = 0; i < 4; ++i) {
      int chunk = wid * 4 + i;
      int row = chunk * 8 + sr;
      gld16(&X[(size_t)(m0 + row) * 512 + kt + sslot * 8], &As[chunk * 8][0]);
      gld16(&W[(size_t)(n0 + row) * 512 + kt + sslot * 8], &Bs[chunk * 8][0]);
    }
    __syncthreads();
#pragma unroll
    for (int kk = 0; kk < 2; ++kk) {
      f16x8 af[4], bf[4];
#pragma unroll
      for (int m = 0; m < 4; ++m)
        af[m] = *(const f16x8*)&As[wr + m * 16 + lr][(((kk * 4 + lg) ^ (lr & 7)) * 8)];
#pragma unroll
      for (int n = 0; n < 4; ++n)
        bf[n] = *(const f16x8*)&Bs[wc + n * 16 + lr][(((kk * 4 + lg) ^ (lr & 7)) * 8)];
#pragma unroll
      for (int m = 0; m < 4; ++m)
#pragma unroll
        for (int n = 0; n < 4; ++n)
          acc[m][n] = MFMA16(bf[n], af[m], acc[m][n]);  // swapped: D[n][m], regs = 4 consecutive n
    }
    __syncthreads();
  }
#pragma unroll
  for (int m = 0; m < 4; ++m)
#pragma unroll
    for (int n = 0; n < 4; ++n) {
      int row = m0 + wr + m * 16 + lr;
      int col = n0 + wc + n * 16 + lg * 4;
      f16x4 o;
      bool relu = (col < 1024);
#pragma unroll
      for (int j = 0; j < 4; ++j) {
        float v = acc[m][n][j];
        if (relu) v = fmaxf(v, 0.f);
        o[j] = (f16)v;
      }
      *(f16x4*)&Out[(size_t)row * QKV_COLS + col] = o;
    }
}

// ---------------- kernel 3: partial K^T V (64x64 per bh) + partial ksum ----------------
// grid (32 bh, 32 splits of 128 rows), 256 threads. fp32 outer-product accumulation.
__global__ __launch_bounds__(256) void k_ktv(
    const f16* __restrict__ qkv, float* __restrict__ partial, float* __restrict__ pksum)
{
  __shared__ f16 ks[32][64];
  __shared__ f16 vs[32][64];
  const int bh = blockIdx.x, sp = blockIdx.y;
  const int b = bh >> 3, h = bh & 7;
  const int tid = threadIdx.x, wid = tid >> 6, lane = tid & 63;
  const int srow = lane >> 3, scol = (lane & 7) * 8;
  const int td = (wid << 2) | (lane >> 4);
  const int te = lane & 15;
  float acc[4][4] = {};
  float ksacc[4] = {0.f, 0.f, 0.f, 0.f};
  const size_t rowbase = (size_t)b * N_ + sp * 128;
  for (int t = 0; t < 4; ++t) {
    int nb = t * 32 + wid * 8 + srow;
    gld16(&qkv[(rowbase + nb) * QKV_COLS + 512 + h * 64 + scol], &ks[wid * 8][0]);
    gld16(&qkv[(rowbase + nb) * QKV_COLS + 1024 + h * 64 + scol], &vs[wid * 8][0]);
    __syncthreads();
#pragma unroll 4
    for (int n = 0; n < 32; ++n) {
      f16x4 kd = *(const f16x4*)&ks[n][td * 4];
      f16x4 ve = *(const f16x4*)&vs[n][te * 4];
      float kf[4], vf[4];
#pragma unroll
      for (int i = 0; i < 4; ++i) { kf[i] = (float)kd[i]; vf[i] = (float)ve[i]; }
#pragma unroll
      for (int i = 0; i < 4; ++i)
#pragma unroll
        for (int j = 0; j < 4; ++j)
          acc[i][j] += kf[i] * vf[j];
      if (te == 0) {
#pragma unroll
        for (int i = 0; i < 4; ++i) ksacc[i] += kf[i];
      }
    }
    __syncthreads();
  }
  float* pp = partial + (size_t)(bh * 32 + sp) * 4096;
#pragma unroll
  for (int i = 0; i < 4; ++i)
#pragma unroll
    for (int j = 0; j < 4; ++j)
      pp[(td * 4 + i) * 64 + te * 4 + j] = acc[i][j];
  if (te == 0) {
    float* kp = pksum + (bh * 32 + sp) * 64;
#pragma unroll
    for (int i = 0; i < 4; ++i) kp[td * 4 + i] = ksacc[i];
  }
}

// ---------------- kernel 4: reduce 32 partials (deterministic) ----------------
__global__ __launch_bounds__(256) void k_reduce(
    const float* __restrict__ partial, const float* __restrict__ pksum,
    float* __restrict__ attn_acc, float* __restrict__ ksum)
{
  const int bh = blockIdx.x, seg = blockIdx.y, tid = threadIdx.x;
  const int i = seg * 256 + tid;
  float s = 0.f;
#pragma unroll 8
  for (int sp = 0; sp < 32; ++sp) s += partial[(size_t)(bh * 32 + sp) * 4096 + i];
  attn_acc[bh * 4096 + i] = s;
  if (seg == 0 && tid < 64) {
    float t2 = 0.f;
#pragma unroll 8
    for (int sp = 0; sp < 32; ++sp) t2 += pksum[(bh * 32 + sp) * 64 + tid];
    ksum[bh * 64 + tid] = t2;
  }
}

// ---------------- kernel 5: attn1 = q @ (attn*temp); denom; outputs ----------------
// grid (32 bh, 16 n-splits of 256 rows), 256 threads. Swizzled attnT, swapped MFMA.
__global__ __launch_bounds__(256) void k_attn1(
    const f16* __restrict__ qkv, const float* __restrict__ attn_acc,
    const float* __restrict__ ksum, const float* __restrict__ temp,
    float* __restrict__ attn1_out, f16* __restrict__ outh)
{
  __shared__ f16 attnT[64][64];   // attnT[e][slot-swizzled d] = attn[d][e] * temp[h]
  __shared__ float ksum_s[64];
  __shared__ float denom_s[256];
  const int bh = blockIdx.x, sp = blockIdx.y;
  const int b = bh >> 3, h = bh & 7;
  const int tid = threadIdx.x, wid = tid >> 6, lane = tid & 63;
  const int lr = lane & 15, lg = lane >> 4;
  const int n0 = sp * 256;
  const float tscale = temp[h];
  {
    // conflict-free transpose fill: thread -> row e, 16-wide d block
    int e = tid & 63, dblk = (tid >> 6) * 16;
    float vals[16];
#pragma unroll
    for (int x = 0; x < 16; ++x)
      vals[x] = attn_acc[bh * 4096 + (dblk + x) * 64 + e] * tscale;  // coalesced over e
#pragma unroll
    for (int half = 0; half < 2; ++half) {
      int slot = ((dblk >> 3) + half) ^ (e & 7);
      f16x8 pk;
#pragma unroll
      for (int j = 0; j < 8; ++j) pk[j] = (f16)vals[half * 8 + j];
      *(f16x8*)&attnT[e][slot * 8] = pk;
    }
  }
  if (tid < 64) ksum_s[tid] = ksum[bh * 64 + tid];
  __syncthreads();
  {  // denom for this thread's row
    size_t row = (size_t)b * N_ + n0 + tid;
    const f16* qrow = &qkv[row * QKV_COLS + h * 64];
    float dot = 0.f;
#pragma unroll
    for (int d0 = 0; d0 < 64; d0 += 8) {
      f16x8 qv = *(const f16x8*)&qrow[d0];
#pragma unroll
      for (int j = 0; j < 8; ++j) dot += (float)qv[j] * ksum_s[d0 + j];
    }
    denom_s[tid] = fmaxf(dot, 100.f);
  }
  // attnT fragments (A-operand after swap): rows = e, k = d (swizzled slots)
  f16x8 bf[4][2];
#pragma unroll
  for (int et = 0; et < 4; ++et)
#pragma unroll
    for (int kk = 0; kk < 2; ++kk) {
      int e = et * 16 + lr;
      bf[et][kk] = *(const f16x8*)&attnT[e][(((kk * 4 + lg) ^ (e & 7)) * 8)];
    }
  __syncthreads();
  f32x4 acc[4][4] = {};
#pragma unroll
  for (int mt = 0; mt < 4; ++mt) {
    size_t rbase = ((size_t)b * N_ + n0 + wid * 64 + mt * 16 + lr) * QKV_COLS + h * 64;
#pragma unroll
    for (int kk = 0; kk < 2; ++kk) {
      f16x8 a = *(const f16x8*)&qkv[rbase + kk * 32 + lg * 8];
#pragma unroll
      for (int et = 0; et < 4; ++et)
        acc[mt][et] = MFMA16(bf[et][kk], a, acc[mt][et]);  // swapped: D[e][n]
    }
  }
#pragma unroll
  for (int mt = 0; mt < 4; ++mt) {
    int rl = wid * 64 + mt * 16 + lr;   // local q row
    int n = n0 + rl;
    float dn = denom_s[rl];
#pragma unroll
    for (int et = 0; et < 4; ++et) {
      int e = et * 16 + lg * 4;
      float4 o;
      f16x4 oh;
      o.x = acc[mt][et][0]; o.y = acc[mt][et][1]; o.z = acc[mt][et][2]; o.w = acc[mt][et][3];
#pragma unroll
      for (int j = 0; j < 4; ++j) oh[j] = (f16)(acc[mt][et][j] / dn);
      *(float4*)&attn1_out[((size_t)bh * N_ + n) * 64 + e] = o;
      *(f16x4*)&outh[((size_t)b * N_ + n) * 512 + h * 64 + e] = oh;
    }
  }
}

// ---------------- kernel 6: proj GEMM  Y(16384x512) = out(16384x512) @ Wproj(512x512)^T + b
__global__ __launch_bounds__(256) void k_proj_gemm(
    const f16* __restrict__ X, const f16* __restrict__ W,
    const float* __restrict__ bias, float* __restrict__ Y)
{
  __shared__ f16 As[128][64];
  __shared__ f16 Bs[128][64];
  // XCD swizzle: 512 blocks, 64 consecutive work-ids per XCD
  int w = (blockIdx.x & 7) * 64 + (blockIdx.x >> 3);
  const int n0 = (w % 4) * 128;
  const int m0 = (w / 4) * 128;
  const int tid = threadIdx.x;
  const int wid = tid >> 6;
  const int lane = tid & 63;
  const int lr = lane & 15, lg = lane >> 4;
  const int sr = lane >> 3;
  const int sslot = (lane & 7) ^ sr;
  const int wr = (wid >> 1) * 64, wc = (wid & 1) * 64;
  f32x4 acc[4][4] = {};
  for (int kt = 0; kt < 512; kt += 64) {
#pragma unroll
    for (int i = 0; i < 4; ++i) {
      int chunk = wid * 4 + i;
      int row = chunk * 8 + sr;
      gld16(&X[(size_t)(m0 + row) * 512 + kt + sslot * 8], &As[chunk * 8][0]);
      gld16(&W[(size_t)(n0 + row) * 512 + kt + sslot * 8], &Bs[chunk * 8][0]);
    }
    __syncthreads();
#pragma unroll
    for (int kk = 0; kk < 2; ++kk) {
      f16x8 af[4], bf[4];
#pragma unroll
      for (int m = 0; m < 4; ++m)
        af[m] = *(const f16x8*)&As[wr + m * 16 + lr][(((kk * 4 + lg) ^ (lr & 7)) * 8)];
#pragma unroll
      for (int n = 0; n < 4; ++n)
        bf[n] = *(const f16x8*)&Bs[wc + n * 16 + lr][(((kk * 4 + lg) ^ (lr & 7)) * 8)];
#pragma unroll
      for (int m = 0; m < 4; ++m)
#pragma unroll
        for (int n = 0; n < 4; ++n)
          acc[m][n] = MFMA16(bf[n], af[m], acc[m][n]);  // swapped
    }
    __syncthreads();
  }
#pragma unroll
  for (int m = 0; m < 4; ++m)
#pragma unroll
    for (int n = 0; n < 4; ++n) {
      int row = m0 + wr + m * 16 + lr;
      int col = n0 + wc + n * 16 + lg * 4;
      float4 o;
      o.x = acc[m][n][0] + bias[col + 0];
      o.y = acc[m][n][1] + bias[col + 1];
      o.z = acc[m][n][2] + bias[col + 2];
      o.w = acc[m][n][3] + bias[col + 3];
      *(float4*)&Y[(size_t)row * C_ + col] = o;
    }
}

extern "C" void kernel_launch(void* const* d_in, const int* in_sizes, int n_in,
                              void* d_out, int out_size, void* d_ws, size_t ws_size,
                              hipStream_t stream)
{
  const float* x     = (const float*)d_in[0];
  const float* wqkv  = (const float*)d_in[1];
  const float* temp  = (const float*)d_in[2];
  const float* wproj = (const float*)d_in[3];
  const float* bproj = (const float*)d_in[4];
  float* y_out     = (float*)d_out;
  float* attn1_out = (float*)d_out + 8388608;

  char* ws = (char*)d_ws;
  f16*   xh       = (f16*)(ws);                   // 16777216 B (reused as `partial` after QKV GEMM)
  float* partial  = (float*)(ws);                 // 32*32*4096*4 = 16777216 B, aliases xh
  f16*   wqkvh    = (f16*)(ws + 16777216);        // 1572864
  f16*   wprojh   = (f16*)(ws + 18350080);        // 524288
  f16*   qkvh     = (f16*)(ws + 18874368);        // 50331648
  float* attn_acc = (float*)(ws + 69206016);      // 524288
  float* ksum     = (float*)(ws + 69730304);      // 8192
  float* pksum    = (float*)(ws + 69738496);      // 262144
  f16*   outh     = (f16*)(ws + 70000640);        // 16777216 (end 86777856)

  hipLaunchKernelGGL(k_convert,  dim3(2048),    dim3(256), 0, stream, x, wqkv, wproj, xh, wqkvh, wprojh);
  hipLaunchKernelGGL(k_qkv_gemm, dim3(1536),    dim3(256), 0, stream, xh, wqkvh, qkvh);
  hipLaunchKernelGGL(k_ktv,      dim3(32, 32),  dim3(256), 0, stream, qkvh, partial, pksum);
  hipLaunchKernelGGL(k_reduce,   dim3(32, 16),  dim3(256), 0, stream, partial, pksum, attn_acc, ksum);
  hipLaunchKernelGGL(k_attn1,    dim3(32, 16),  dim3(256), 0, stream, qkvh, attn_acc, ksum, temp, attn1_out, outh);
  hipLaunchKernelGGL(k_proj_gemm,dim3(512),     dim3(256), 0, stream, outh, wprojh, bproj, y_out);
}